// Round 6
// baseline (664.036 us; speedup 1.0000x reference)
//
#include <hip/hip_runtime.h>
#include <math.h>

#define T_TOKENS 16384
#define HID      4096
#define NEXP     256
#define NGROUP   8
#define GSIZE    32
#define TOPKG    4
#define TOPK     8
#define RSCALE   2.5f

#define TAU   2e-5f      // expert-score margin (validated R5)
#define TAUG  3e-5f      // group-score margin  (validated R5)

// ---- split-K GEMM config ----
#define BM     64
#define BK     32
#define SPLITK 4
#define KSPAN  (HID / SPLITK)    // 1024
#define NKS    (KSPAN / BK)      // 32 K-steps per block
// padded frag-major staging (ushort units): bank-floor on writes AND reads
#define CSTR   136               // kchunk stride (unpadded 128)
#define TSTR   544               // 16-row tile stride = 4*CSTR
#define A_HI   0
#define A_LO   2176              // 4 tiles * 544
#define B_HI   4352
#define B_LO   13056             // B_HI + 16*544
#define STG_TOT 21760            // ushorts = 43520 B -> 3 blocks/CU

typedef __attribute__((ext_vector_type(8))) short bf16x8;
typedef __attribute__((ext_vector_type(4))) float f32x4;

// staging address for (row r, float4-slot q): same (lane,elem)->k map for A and B
__device__ __forceinline__ int stoff(int r, int q) {
    return (r >> 4) * TSTR + (q >> 1) * CSTR + (r & 15) * 8 + (q & 1) * 4;
}
// frag read offset for lane within a 16-row tile
__device__ __forceinline__ int froff(int lane) {
    return (lane >> 4) * CSTR + (lane & 15) * 8;
}

// Split float4 into packed bf16 hi (RNE) and lo (RNE of exact residual).
__device__ __forceinline__ void split4(const float4 v, uint& h01, uint& h23,
                                       uint& l01, uint& l23) {
    const uint u0 = __float_as_uint(v.x) + 0x8000u;
    const uint u1 = __float_as_uint(v.y) + 0x8000u;
    const uint u2 = __float_as_uint(v.z) + 0x8000u;
    const uint u3 = __float_as_uint(v.w) + 0x8000u;
    h01 = __builtin_amdgcn_perm(u1, u0, 0x07060302u);
    h23 = __builtin_amdgcn_perm(u3, u2, 0x07060302u);
    const float f0 = v.x - __uint_as_float(u0 & 0xFFFF0000u);
    const float f1 = v.y - __uint_as_float(u1 & 0xFFFF0000u);
    const float f2 = v.z - __uint_as_float(u2 & 0xFFFF0000u);
    const float f3 = v.w - __uint_as_float(u3 & 0xFFFF0000u);
    l01 = __builtin_amdgcn_perm(__float_as_uint(f1) + 0x8000u,
                                __float_as_uint(f0) + 0x8000u, 0x07060302u);
    l23 = __builtin_amdgcn_perm(__float_as_uint(f3) + 0x8000u,
                                __float_as_uint(f2) + 0x8000u, 0x07060302u);
}

// ---- shared routing decision (identical in all paths; validated R5) ----
template <class SC>
__device__ __forceinline__ bool route_core(SC sc, const float* __restrict__ bias,
                                           int* id, float* wv)
{
    float gs[NGROUP];
#pragma unroll
    for (int g = 0; g < NGROUP; ++g) {
        float m1 = -1e30f, m2 = -1e30f;
        for (int i = 0; i < GSIZE; ++i) {
            const int e = g * GSIZE + i;
            const float v = sc(e) + bias[e];
            if (v > m1)      { m2 = m1; m1 = v; }
            else if (v > m2) { m2 = v; }
        }
        gs[g] = m1 + m2;
    }

    unsigned gmask = 0;
    float g4 = -1e30f;
#pragma unroll
    for (int r = 0; r < TOPKG; ++r) {
        int bi = 0; float bv = -1e30f;
#pragma unroll
        for (int g = 0; g < NGROUP; ++g) {
            const bool taken = (gmask >> g) & 1;
            if (!taken && gs[g] > bv) { bv = gs[g]; bi = g; }
        }
        gmask |= 1u << bi;
        g4 = bv;
    }
    float g5 = -1e30f;
#pragma unroll
    for (int g = 0; g < NGROUP; ++g)
        if (!((gmask >> g) & 1) && gs[g] > g5) g5 = gs[g];

    float val[TOPK + 1]; int vid[TOPK + 1];
#pragma unroll
    for (int r = 0; r <= TOPK; ++r) { val[r] = -1e30f; vid[r] = 0; }
    for (int e = 0; e < NEXP; ++e) {
        const bool allowed = (gmask >> (e >> 5)) & 1;
        const float v = allowed ? (sc(e) + bias[e]) : 0.0f;
        if (v > val[TOPK]) {
#pragma unroll
            for (int p = TOPK; p >= 1; --p) {
                if (v > val[p - 1])  { val[p] = val[p - 1]; vid[p] = vid[p - 1]; }
                else if (v > val[p]) { val[p] = v;          vid[p] = e; }
            }
            if (v > val[0]) { val[0] = v; vid[0] = e; }
        }
    }

    bool tight = (g4 - g5 < TAUG);
#pragma unroll
    for (int i = 0; i < TOPK; ++i) tight |= (val[i] - val[i + 1] < TAU);

    float sum = 0.0f;
#pragma unroll
    for (int r = 0; r < TOPK; ++r) { id[r] = vid[r]; wv[r] = sc(vid[r]); sum += wv[r]; }
    const float inv = RSCALE / (sum + 1e-20f);
#pragma unroll
    for (int r = 0; r < TOPK; ++r) wv[r] *= inv;
    return tight;
}

// exact fp32 recompute + route for one token (cold fallback only)
__device__ void exact_token(const float* __restrict__ hs, const float* __restrict__ wt,
                            const float* __restrict__ bias, float* __restrict__ out, int t)
{
    float lg[NEXP];
    const float* hrow = hs + (size_t)t * HID;
    for (int e = 0; e < NEXP; ++e) {
        const float* wr = wt + (size_t)e * HID;
        float a = 0.0f;
        for (int k = 0; k < HID; k += 4) {
            const float4 x = *(const float4*)(hrow + k);
            const float4 b = *(const float4*)(wr + k);
            a = fmaf(x.x, b.x, a); a = fmaf(x.y, b.y, a);
            a = fmaf(x.z, b.z, a); a = fmaf(x.w, b.w, a);
        }
        lg[e] = 1.0f / (1.0f + expf(-a));
    }
    int id[TOPK]; float wv[TOPK];
    route_core([&](int e) { return lg[e]; }, bias, id, wv);
    for (int r = 0; r < TOPK; ++r) {
        out[(size_t)t * TOPK + r] = (float)id[r];
        out[(size_t)T_TOKENS * TOPK + (size_t)t * TOPK + r] = wv[r];
    }
}

// =============== split-K GEMM: partial logits -> pw[s][t][e] ===============
__global__ __launch_bounds__(256, 2)
void router_gemm(const float* __restrict__ hs, const float* __restrict__ wt,
                 float* __restrict__ pw)
{
    __shared__ ushort u16[STG_TOT];

    const int tid  = threadIdx.x;
    const int lane = tid & 63;
    const int w    = tid >> 6;            // wave -> experts w*64..w*64+63
    const int m    = blockIdx.x >> 2;
    const int sk   = blockIdx.x & 3;      // K-split id
    const int t0   = m * BM;
    const int kb0  = sk * KSPAN;
    const int r0   = tid >> 3;            // 0..31
    const int q    = tid & 7;             // float4 slot

    f32x4 acc[4][4];
#pragma unroll
    for (int i = 0; i < 4; ++i)
#pragma unroll
        for (int j = 0; j < 4; ++j) acc[i][j] = (f32x4)0.0f;

    float4 ra[2], rb[8];
#pragma unroll
    for (int s = 0; s < 2; ++s)
        ra[s] = *(const float4*)(hs + (size_t)(t0 + r0 + 32 * s) * HID + kb0 + q * 4);
#pragma unroll
    for (int i = 0; i < 8; ++i)
        rb[i] = *(const float4*)(wt + (size_t)(r0 + 32 * i) * HID + kb0 + q * 4);

    for (int ks = 0; ks < NKS; ++ks) {
        __syncthreads();   // previous compute done; LDS reusable

        // ---- convert regs -> bf16 hi/lo, write padded frag-major LDS (bank-floor) ----
#pragma unroll
        for (int s = 0; s < 2; ++s) {
            const int r = r0 + 32 * s;
            uint h01, h23, l01, l23;
            split4(ra[s], h01, h23, l01, l23);
            const int eo = stoff(r, q);
            uint2 hv; hv.x = h01; hv.y = h23;
            uint2 lv; lv.x = l01; lv.y = l23;
            *(uint2*)&u16[A_HI + eo] = hv;
            *(uint2*)&u16[A_LO + eo] = lv;
        }
#pragma unroll
        for (int i = 0; i < 8; ++i) {
            const int r = r0 + 32 * i;
            uint h01, h23, l01, l23;
            split4(rb[i], h01, h23, l01, l23);
            const int eo = stoff(r, q);
            uint2 hv; hv.x = h01; hv.y = h23;
            uint2 lv; lv.x = l01; lv.y = l23;
            *(uint2*)&u16[B_HI + eo] = hv;
            *(uint2*)&u16[B_LO + eo] = lv;
        }
        __syncthreads();

        // ---- prefetch next K-step ----
        if (ks + 1 < NKS) {
            const int kb = kb0 + (ks + 1) * BK;
#pragma unroll
            for (int s = 0; s < 2; ++s)
                ra[s] = *(const float4*)(hs + (size_t)(t0 + r0 + 32 * s) * HID + kb + q * 4);
#pragma unroll
            for (int i = 0; i < 8; ++i)
                rb[i] = *(const float4*)(wt + (size_t)(r0 + 32 * i) * HID + kb + q * 4);
        }

        // ---- frag reads (bank-floor) + 48 MFMA/wave (3-limb split product) ----
        const int fo = froff(lane);
        bf16x8 ah[4], al[4];
#pragma unroll
        for (int rt = 0; rt < 4; ++rt) {
            ah[rt] = *(const bf16x8*)&u16[A_HI + rt * TSTR + fo];
            al[rt] = *(const bf16x8*)&u16[A_LO + rt * TSTR + fo];
        }
#pragma unroll
        for (int c = 0; c < 4; ++c) {
            const int ct = w * 4 + c;
            const bf16x8 bh = *(const bf16x8*)&u16[B_HI + ct * TSTR + fo];
            const bf16x8 bl = *(const bf16x8*)&u16[B_LO + ct * TSTR + fo];
#pragma unroll
            for (int rt = 0; rt < 4; ++rt) {
                acc[rt][c] = __builtin_amdgcn_mfma_f32_16x16x32_bf16(ah[rt], bh, acc[rt][c], 0, 0, 0);
                acc[rt][c] = __builtin_amdgcn_mfma_f32_16x16x32_bf16(ah[rt], bl, acc[rt][c], 0, 0, 0);
                acc[rt][c] = __builtin_amdgcn_mfma_f32_16x16x32_bf16(al[rt], bh, acc[rt][c], 0, 0, 0);
            }
        }
    }

    // ---- store raw partial logits (no sigmoid): pw[sk][token][expert] ----
#pragma unroll
    for (int rt = 0; rt < 4; ++rt)
#pragma unroll
        for (int c = 0; c < 4; ++c) {
            const int col  = w * 64 + c * 16 + (lane & 15);
            const int rowb = rt * 16 + (lane >> 4) * 4;
#pragma unroll
            for (int j = 0; j < 4; ++j)
                pw[((size_t)(sk * T_TOKENS) + t0 + rowb + j) * NEXP + col] = acc[rt][c][j];
        }
}

// =============== routing: sum partials -> sigmoid -> route ===============
__global__ __launch_bounds__(256, 2)
void router_route(const float* __restrict__ pw, const float* __restrict__ bias,
                  float* __restrict__ out,
                  unsigned* __restrict__ wcnt, unsigned* __restrict__ wlist,
                  unsigned cap)
{
    __shared__ float Lg[NEXP * 64];      // [expert][token] add-swizzled, 64 KB
    const int tid = threadIdx.x;
    const int t0  = blockIdx.x * 64;

#pragma unroll 8
    for (int t = 0; t < 64; ++t) {
        float v = 0.0f;
#pragma unroll
        for (int s = 0; s < SPLITK; ++s)
            v += pw[((size_t)(s * T_TOKENS) + t0 + t) * NEXP + tid];
        Lg[tid * 64 + ((t + tid) & 63)] = 1.0f / (1.0f + expf(-v));
    }
    __syncthreads();

    if (tid < 64) {
        const int t = t0 + tid;
        int id[TOPK]; float wv[TOPK];
        const bool tight = route_core(
            [&](int e) { return Lg[e * 64 + ((tid + e) & 63)]; }, bias, id, wv);

#pragma unroll
        for (int r = 0; r < TOPK; ++r) {
            out[(size_t)t * TOPK + r] = (float)id[r];
            out[(size_t)T_TOKENS * TOPK + (size_t)t * TOPK + r] = wv[r];
        }
        if (tight) {
            const unsigned pos = atomicAdd(wcnt, 1u);
            if (pos < cap) wlist[pos] = (unsigned)t;   // cap=16384 -> never overflows
        }
    }
}

// =============== cleanup: exact fp32 recompute, 8 tokens per block-pass ===============
__global__ __launch_bounds__(256, 2)
void router_exact(const float* __restrict__ hs, const float* __restrict__ wt,
                  const float* __restrict__ bias, float* __restrict__ out,
                  const unsigned* __restrict__ wcnt, const unsigned* __restrict__ wlist,
                  unsigned cap)
{
    __shared__ float lg[8][NEXP + 1];
    __shared__ int   toks[8];
    const unsigned count = min(*wcnt, cap);
    const int tid = threadIdx.x;

    for (unsigned base = blockIdx.x * 8u; base < count; base += gridDim.x * 8u) {
        const unsigned n = min(8u, count - base);
        __syncthreads();                               // protect prev-iter lg/toks
        if (tid < 8) toks[tid] = (int)wlist[base + min((unsigned)tid, n - 1)];
        __syncthreads();

        const float* wr = wt + (size_t)tid * HID;      // thread = expert
        const float* hp[8];
#pragma unroll
        for (int j = 0; j < 8; ++j) hp[j] = hs + (size_t)toks[j] * HID;

        float a[8] = {0.f, 0.f, 0.f, 0.f, 0.f, 0.f, 0.f, 0.f};
        for (int k = 0; k < HID; k += 4) {
            const float4 b = *(const float4*)(wr + k);
#pragma unroll
            for (int j = 0; j < 8; ++j) {              // hs loads wave-uniform (broadcast)
                const float4 x = *(const float4*)(hp[j] + k);
                a[j] = fmaf(x.x, b.x, a[j]); a[j] = fmaf(x.y, b.y, a[j]);
                a[j] = fmaf(x.z, b.z, a[j]); a[j] = fmaf(x.w, b.w, a[j]);
            }
        }
#pragma unroll
        for (int j = 0; j < 8; ++j) lg[j][tid] = 1.0f / (1.0f + expf(-a[j]));
        __syncthreads();

        if (tid < (int)n) {
            const int t = toks[tid];
            int id[TOPK]; float wv[TOPK];
            route_core([&](int e) { return lg[tid][e]; }, bias, id, wv);
            for (int r = 0; r < TOPK; ++r) {
                out[(size_t)t * TOPK + r] = (float)id[r];
                out[(size_t)T_TOKENS * TOPK + (size_t)t * TOPK + r] = wv[r];
            }
        }
    }
}

// =============== fallback monolith (R5-validated) ===============
__global__ __launch_bounds__(512, 1)
void router_mono(const float* __restrict__ hs, const float* __restrict__ wt,
                 const float* __restrict__ bias, float* __restrict__ out,
                 unsigned* __restrict__ wcnt, unsigned* __restrict__ wlist, unsigned cap)
{
    __shared__ float smem[16384];
    ushort* u16 = (ushort*)smem;
    float*  Lg  = smem;

    const int tid  = threadIdx.x;
    const int lane = tid & 63;
    const int w    = tid >> 6;
    const int t0   = blockIdx.x * 64;
    const int ar   = tid >> 3;
    const int aq   = tid & 7;

    f32x4 acc[4][2];
#pragma unroll
    for (int i = 0; i < 4; ++i)
#pragma unroll
        for (int j = 0; j < 2; ++j) acc[i][j] = (f32x4)0.0f;

    float4 ra, rb[4];
    ra = *(const float4*)(hs + (size_t)(t0 + ar) * HID + aq * 4);
#pragma unroll
    for (int s = 0; s < 4; ++s)
        rb[s] = *(const float4*)(wt + (size_t)(ar + s * 64) * HID + aq * 4);

    for (int ks = 0; ks < HID / BK; ++ks) {
        __syncthreads();
        {
            uint h01, h23, l01, l23;
            split4(ra, h01, h23, l01, l23);
            const int eo = (ar >> 4) * 512 + (aq >> 1) * 128 + (ar & 15) * 8 + (aq & 1) * 4;
            uint2 hv; hv.x = h01; hv.y = h23;
            uint2 lv; lv.x = l01; lv.y = l23;
            *(uint2*)&u16[0 + eo] = hv;
            *(uint2*)&u16[2048 + eo] = lv;
        }
#pragma unroll
        for (int s = 0; s < 4; ++s) {
            const int e = ar + s * 64;
            uint h01, h23, l01, l23;
            split4(rb[s], h01, h23, l01, l23);
            const int eo = (e >> 4) * 512 + (aq >> 1) * 128 + (e & 15) * 8 + (aq & 1) * 4;
            uint2 hv; hv.x = h01; hv.y = h23;
            uint2 lv; lv.x = l01; lv.y = l23;
            *(uint2*)&u16[4096 + eo] = hv;
            *(uint2*)&u16[12288 + eo] = lv;
        }
        __syncthreads();
        if (ks + 1 < HID / BK) {
            const int k0 = (ks + 1) * BK;
            ra = *(const float4*)(hs + (size_t)(t0 + ar) * HID + k0 + aq * 4);
#pragma unroll
            for (int s = 0; s < 4; ++s)
                rb[s] = *(const float4*)(wt + (size_t)(ar + s * 64) * HID + k0 + aq * 4);
        }
        bf16x8 ah[4], al[4];
#pragma unroll
        for (int rt = 0; rt < 4; ++rt) {
            ah[rt] = *(const bf16x8*)&u16[0 + rt * 512 + lane * 8];
            al[rt] = *(const bf16x8*)&u16[2048 + rt * 512 + lane * 8];
        }
#pragma unroll
        for (int c = 0; c < 2; ++c) {
            const int ct = w * 2 + c;
            const bf16x8 bh = *(const bf16x8*)&u16[4096 + ct * 512 + lane * 8];
            const bf16x8 bl = *(const bf16x8*)&u16[12288 + ct * 512 + lane * 8];
#pragma unroll
            for (int rt = 0; rt < 4; ++rt) {
                acc[rt][c] = __builtin_amdgcn_mfma_f32_16x16x32_bf16(ah[rt], bh, acc[rt][c], 0, 0, 0);
                acc[rt][c] = __builtin_amdgcn_mfma_f32_16x16x32_bf16(ah[rt], bl, acc[rt][c], 0, 0, 0);
                acc[rt][c] = __builtin_amdgcn_mfma_f32_16x16x32_bf16(al[rt], bh, acc[rt][c], 0, 0, 0);
            }
        }
    }
    __syncthreads();
#pragma unroll
    for (int rt = 0; rt < 4; ++rt)
#pragma unroll
        for (int c = 0; c < 2; ++c) {
            const int col  = w * 32 + c * 16 + (lane & 15);
            const int rowb = rt * 16 + (lane >> 4) * 4;
#pragma unroll
            for (int j = 0; j < 4; ++j) {
                const int row = rowb + j;
                Lg[col * 64 + ((row + col) & 63)] = 1.0f / (1.0f + expf(-acc[rt][c][j]));
            }
        }
    __syncthreads();

    if (tid < 64) {
        const int t = t0 + tid;
        int id[TOPK]; float wv[TOPK];
        const bool tight = route_core(
            [&](int e) { return Lg[e * 64 + ((tid + e) & 63)]; }, bias, id, wv);
#pragma unroll
        for (int r = 0; r < TOPK; ++r) {
            out[(size_t)t * TOPK + r] = (float)id[r];
            out[(size_t)T_TOKENS * TOPK + (size_t)t * TOPK + r] = wv[r];
        }
        if (tight) {
            bool queued = false;
            if (wcnt) {
                const unsigned pos = atomicAdd(wcnt, 1u);
                if (pos < cap) { wlist[pos] = (unsigned)t; queued = true; }
            }
            if (!queued) exact_token(hs, wt, bias, out, t);
        }
    }
}

extern "C" void kernel_launch(void* const* d_in, const int* in_sizes, int n_in,
                              void* d_out, int out_size, void* d_ws, size_t ws_size,
                              hipStream_t stream) {
    const float* hs   = (const float*)d_in[0];   // [16384, 4096] f32
    const float* wt   = (const float*)d_in[1];   // [256, 4096]   f32
    const float* bias = (const float*)d_in[2];   // [256]         f32
    float* out = (float*)d_out;
    (void)in_sizes; (void)n_in; (void)out_size;

    const size_t PW_BYTES = (size_t)SPLITK * T_TOKENS * NEXP * 4;   // 64 MB
    const size_t NEED = PW_BYTES + 4 + (size_t)T_TOKENS * 4;

    if (ws_size >= NEED) {
        float*    pw    = (float*)d_ws;
        unsigned* wcnt  = (unsigned*)((char*)d_ws + PW_BYTES);
        unsigned* wlist = wcnt + 1;
        hipMemsetAsync(wcnt, 0, sizeof(unsigned), stream);
        router_gemm<<<(T_TOKENS / BM) * SPLITK, 256, 0, stream>>>(hs, wt, pw);
        router_route<<<T_TOKENS / 64, 256, 0, stream>>>(pw, bias, out, wcnt, wlist,
                                                        (unsigned)T_TOKENS);
        router_exact<<<256, 256, 0, stream>>>(hs, wt, bias, out, wcnt, wlist,
                                              (unsigned)T_TOKENS);
    } else if (ws_size >= 8) {
        unsigned cap = (unsigned)((ws_size - 4) / 4);
        if (cap > T_TOKENS) cap = T_TOKENS;
        unsigned* wcnt  = (unsigned*)d_ws;
        unsigned* wlist = wcnt + 1;
        hipMemsetAsync(d_ws, 0, sizeof(unsigned), stream);
        router_mono<<<T_TOKENS / 64, 512, 0, stream>>>(hs, wt, bias, out, wcnt, wlist, cap);
        router_exact<<<256, 256, 0, stream>>>(hs, wt, bias, out, wcnt, wlist, cap);
    } else {
        router_mono<<<T_TOKENS / 64, 512, 0, stream>>>(hs, wt, bias, out,
                                                       nullptr, nullptr, 0u);
    }
}

// Round 7
// 450.055 us; speedup vs baseline: 1.4755x; 1.4755x over previous
//
#include <hip/hip_runtime.h>
#include <math.h>

#define T_TOKENS 16384
#define HID      4096
#define NEXP     256
#define NGROUP   8
#define GSIZE    32
#define TOPKG    4
#define TOPK     8
#define RSCALE   2.5f

#define TAU   2e-5f      // expert-score margin (validated R5/R6)
#define TAUG  3e-5f      // group-score margin  (validated R5/R6)

// ---- split-K GEMM config (unchanged from R6, known-good) ----
#define BM     64
#define BK     32
#define SPLITK 4
#define KSPAN  (HID / SPLITK)    // 1024
#define NKS    (KSPAN / BK)      // 32 K-steps per block
#define CSTR   136               // kchunk stride (unpadded 128)
#define TSTR   544               // 16-row tile stride = 4*CSTR
#define A_HI   0
#define A_LO   2176
#define B_HI   4352
#define B_LO   13056
#define STG_TOT 21760            // ushorts = 43520 B

typedef __attribute__((ext_vector_type(8))) short bf16x8;
typedef __attribute__((ext_vector_type(4))) float f32x4;

__device__ __forceinline__ int stoff(int r, int q) {
    return (r >> 4) * TSTR + (q >> 1) * CSTR + (r & 15) * 8 + (q & 1) * 4;
}
__device__ __forceinline__ int froff(int lane) {
    return (lane >> 4) * CSTR + (lane & 15) * 8;
}

__device__ __forceinline__ void split4(const float4 v, uint& h01, uint& h23,
                                       uint& l01, uint& l23) {
    const uint u0 = __float_as_uint(v.x) + 0x8000u;
    const uint u1 = __float_as_uint(v.y) + 0x8000u;
    const uint u2 = __float_as_uint(v.z) + 0x8000u;
    const uint u3 = __float_as_uint(v.w) + 0x8000u;
    h01 = __builtin_amdgcn_perm(u1, u0, 0x07060302u);
    h23 = __builtin_amdgcn_perm(u3, u2, 0x07060302u);
    const float f0 = v.x - __uint_as_float(u0 & 0xFFFF0000u);
    const float f1 = v.y - __uint_as_float(u1 & 0xFFFF0000u);
    const float f2 = v.z - __uint_as_float(u2 & 0xFFFF0000u);
    const float f3 = v.w - __uint_as_float(u3 & 0xFFFF0000u);
    l01 = __builtin_amdgcn_perm(__float_as_uint(f1) + 0x8000u,
                                __float_as_uint(f0) + 0x8000u, 0x07060302u);
    l23 = __builtin_amdgcn_perm(__float_as_uint(f3) + 0x8000u,
                                __float_as_uint(f2) + 0x8000u, 0x07060302u);
}

// ---- shared routing decision (identical in all paths; validated R5/R6) ----
template <class SC>
__device__ __forceinline__ bool route_core(SC sc, const float* __restrict__ bias,
                                           int* id, float* wv)
{
    float gs[NGROUP];
#pragma unroll
    for (int g = 0; g < NGROUP; ++g) {
        float m1 = -1e30f, m2 = -1e30f;
        for (int i = 0; i < GSIZE; ++i) {
            const int e = g * GSIZE + i;
            const float v = sc(e) + bias[e];
            if (v > m1)      { m2 = m1; m1 = v; }
            else if (v > m2) { m2 = v; }
        }
        gs[g] = m1 + m2;
    }

    unsigned gmask = 0;
    float g4 = -1e30f;
#pragma unroll
    for (int r = 0; r < TOPKG; ++r) {
        int bi = 0; float bv = -1e30f;
#pragma unroll
        for (int g = 0; g < NGROUP; ++g) {
            const bool taken = (gmask >> g) & 1;
            if (!taken && gs[g] > bv) { bv = gs[g]; bi = g; }
        }
        gmask |= 1u << bi;
        g4 = bv;
    }
    float g5 = -1e30f;
#pragma unroll
    for (int g = 0; g < NGROUP; ++g)
        if (!((gmask >> g) & 1) && gs[g] > g5) g5 = gs[g];

    float val[TOPK + 1]; int vid[TOPK + 1];
#pragma unroll
    for (int r = 0; r <= TOPK; ++r) { val[r] = -1e30f; vid[r] = 0; }
    for (int e = 0; e < NEXP; ++e) {
        const bool allowed = (gmask >> (e >> 5)) & 1;
        const float v = allowed ? (sc(e) + bias[e]) : 0.0f;
        if (v > val[TOPK]) {
#pragma unroll
            for (int p = TOPK; p >= 1; --p) {
                if (v > val[p - 1])  { val[p] = val[p - 1]; vid[p] = vid[p - 1]; }
                else if (v > val[p]) { val[p] = v;          vid[p] = e; }
            }
            if (v > val[0]) { val[0] = v; vid[0] = e; }
        }
    }

    bool tight = (g4 - g5 < TAUG);
#pragma unroll
    for (int i = 0; i < TOPK; ++i) tight |= (val[i] - val[i + 1] < TAU);

    float sum = 0.0f;
#pragma unroll
    for (int r = 0; r < TOPK; ++r) { id[r] = vid[r]; wv[r] = sc(vid[r]); sum += wv[r]; }
    const float inv = RSCALE / (sum + 1e-20f);
#pragma unroll
    for (int r = 0; r < TOPK; ++r) wv[r] *= inv;
    return tight;
}

// exact fp32 recompute + route for one token (cold fallback only)
__device__ void exact_token(const float* __restrict__ hs, const float* __restrict__ wt,
                            const float* __restrict__ bias, float* __restrict__ out, int t)
{
    float lg[NEXP];
    const float* hrow = hs + (size_t)t * HID;
    for (int e = 0; e < NEXP; ++e) {
        const float* wr = wt + (size_t)e * HID;
        float a = 0.0f;
        for (int k = 0; k < HID; k += 4) {
            const float4 x = *(const float4*)(hrow + k);
            const float4 b = *(const float4*)(wr + k);
            a = fmaf(x.x, b.x, a); a = fmaf(x.y, b.y, a);
            a = fmaf(x.z, b.z, a); a = fmaf(x.w, b.w, a);
        }
        lg[e] = 1.0f / (1.0f + expf(-a));
    }
    int id[TOPK]; float wv[TOPK];
    route_core([&](int e) { return lg[e]; }, bias, id, wv);
    for (int r = 0; r < TOPK; ++r) {
        out[(size_t)t * TOPK + r] = (float)id[r];
        out[(size_t)T_TOKENS * TOPK + (size_t)t * TOPK + r] = wv[r];
    }
}

// =============== split-K GEMM: partial logits -> pw[s][t][e] (unchanged) ===============
__global__ __launch_bounds__(256, 2)
void router_gemm(const float* __restrict__ hs, const float* __restrict__ wt,
                 float* __restrict__ pw)
{
    __shared__ ushort u16[STG_TOT];

    const int tid  = threadIdx.x;
    const int lane = tid & 63;
    const int w    = tid >> 6;
    const int m    = blockIdx.x >> 2;
    const int sk   = blockIdx.x & 3;
    const int t0   = m * BM;
    const int kb0  = sk * KSPAN;
    const int r0   = tid >> 3;
    const int q    = tid & 7;

    f32x4 acc[4][4];
#pragma unroll
    for (int i = 0; i < 4; ++i)
#pragma unroll
        for (int j = 0; j < 4; ++j) acc[i][j] = (f32x4)0.0f;

    float4 ra[2], rb[8];
#pragma unroll
    for (int s = 0; s < 2; ++s)
        ra[s] = *(const float4*)(hs + (size_t)(t0 + r0 + 32 * s) * HID + kb0 + q * 4);
#pragma unroll
    for (int i = 0; i < 8; ++i)
        rb[i] = *(const float4*)(wt + (size_t)(r0 + 32 * i) * HID + kb0 + q * 4);

    for (int ks = 0; ks < NKS; ++ks) {
        __syncthreads();

#pragma unroll
        for (int s = 0; s < 2; ++s) {
            const int r = r0 + 32 * s;
            uint h01, h23, l01, l23;
            split4(ra[s], h01, h23, l01, l23);
            const int eo = stoff(r, q);
            uint2 hv; hv.x = h01; hv.y = h23;
            uint2 lv; lv.x = l01; lv.y = l23;
            *(uint2*)&u16[A_HI + eo] = hv;
            *(uint2*)&u16[A_LO + eo] = lv;
        }
#pragma unroll
        for (int i = 0; i < 8; ++i) {
            const int r = r0 + 32 * i;
            uint h01, h23, l01, l23;
            split4(rb[i], h01, h23, l01, l23);
            const int eo = stoff(r, q);
            uint2 hv; hv.x = h01; hv.y = h23;
            uint2 lv; lv.x = l01; lv.y = l23;
            *(uint2*)&u16[B_HI + eo] = hv;
            *(uint2*)&u16[B_LO + eo] = lv;
        }
        __syncthreads();

        if (ks + 1 < NKS) {
            const int kb = kb0 + (ks + 1) * BK;
#pragma unroll
            for (int s = 0; s < 2; ++s)
                ra[s] = *(const float4*)(hs + (size_t)(t0 + r0 + 32 * s) * HID + kb + q * 4);
#pragma unroll
            for (int i = 0; i < 8; ++i)
                rb[i] = *(const float4*)(wt + (size_t)(r0 + 32 * i) * HID + kb + q * 4);
        }

        const int fo = froff(lane);
        bf16x8 ah[4], al[4];
#pragma unroll
        for (int rt = 0; rt < 4; ++rt) {
            ah[rt] = *(const bf16x8*)&u16[A_HI + rt * TSTR + fo];
            al[rt] = *(const bf16x8*)&u16[A_LO + rt * TSTR + fo];
        }
#pragma unroll
        for (int c = 0; c < 4; ++c) {
            const int ct = w * 4 + c;
            const bf16x8 bh = *(const bf16x8*)&u16[B_HI + ct * TSTR + fo];
            const bf16x8 bl = *(const bf16x8*)&u16[B_LO + ct * TSTR + fo];
#pragma unroll
            for (int rt = 0; rt < 4; ++rt) {
                acc[rt][c] = __builtin_amdgcn_mfma_f32_16x16x32_bf16(ah[rt], bh, acc[rt][c], 0, 0, 0);
                acc[rt][c] = __builtin_amdgcn_mfma_f32_16x16x32_bf16(ah[rt], bl, acc[rt][c], 0, 0, 0);
                acc[rt][c] = __builtin_amdgcn_mfma_f32_16x16x32_bf16(al[rt], bh, acc[rt][c], 0, 0, 0);
            }
        }
    }

#pragma unroll
    for (int rt = 0; rt < 4; ++rt)
#pragma unroll
        for (int c = 0; c < 4; ++c) {
            const int col  = w * 64 + c * 16 + (lane & 15);
            const int rowb = rt * 16 + (lane >> 4) * 4;
#pragma unroll
            for (int j = 0; j < 4; ++j)
                pw[((size_t)(sk * T_TOKENS) + t0 + rowb + j) * NEXP + col] = acc[rt][c][j];
        }
}

// =============== routing: sum partials -> sigmoid -> route (unchanged) ===============
__global__ __launch_bounds__(256, 2)
void router_route(const float* __restrict__ pw, const float* __restrict__ bias,
                  float* __restrict__ out,
                  unsigned* __restrict__ wcnt, unsigned* __restrict__ wlist,
                  unsigned cap)
{
    __shared__ float Lg[NEXP * 64];
    const int tid = threadIdx.x;
    const int t0  = blockIdx.x * 64;

#pragma unroll 8
    for (int t = 0; t < 64; ++t) {
        float v = 0.0f;
#pragma unroll
        for (int s = 0; s < SPLITK; ++s)
            v += pw[((size_t)(s * T_TOKENS) + t0 + t) * NEXP + tid];
        Lg[tid * 64 + ((t + tid) & 63)] = 1.0f / (1.0f + expf(-v));
    }
    __syncthreads();

    if (tid < 64) {
        const int t = t0 + tid;
        int id[TOPK]; float wv[TOPK];
        const bool tight = route_core(
            [&](int e) { return Lg[e * 64 + ((tid + e) & 63)]; }, bias, id, wv);

#pragma unroll
        for (int r = 0; r < TOPK; ++r) {
            out[(size_t)t * TOPK + r] = (float)id[r];
            out[(size_t)T_TOKENS * TOPK + (size_t)t * TOPK + r] = wv[r];
        }
        if (tight) {
            const unsigned pos = atomicAdd(wcnt, 1u);
            if (pos < cap) wlist[pos] = (unsigned)t;
        }
    }
}

// =============== cleanup v2: coalesced wave-per-expert-group fp32 ===============
// 4 tokens/block-pass staged in LDS; wave w owns experts w*64..+63 in groups of 4.
// Raw logits -> lgg (global scratch aliasing dead pw); sigmoid on LDS copy-back.
__global__ __launch_bounds__(256, 2)
void router_exact(const float* __restrict__ hs, const float* __restrict__ wt,
                  const float* __restrict__ bias, float* __restrict__ out,
                  const unsigned* __restrict__ wcnt, const unsigned* __restrict__ wlist,
                  float* __restrict__ lgg, unsigned cap)
{
    __shared__ float hs4[4][HID];        // 64 KB; reused as lg[4][257] after compute
    const unsigned count = min(*wcnt, cap);
    const int tid  = threadIdx.x;
    const int lane = tid & 63;
    const int w    = tid >> 6;

    for (unsigned base = blockIdx.x * 4u; base < count; base += gridDim.x * 4u) {
        __syncthreads();                 // protect hs4 reuse across passes
        const unsigned n = (count - base < 4u) ? (count - base) : 4u;
        unsigned pos[4]; int toks[4];
#pragma unroll
        for (int s = 0; s < 4; ++s) {
            pos[s]  = base + (((unsigned)s < n - 1) ? (unsigned)s : (n - 1));
            toks[s] = (int)wlist[pos[s]];   // broadcast loads (uniform)
        }

        // ---- stage 4 hs rows -> LDS (coalesced float4) ----
#pragma unroll
        for (int s = 0; s < 4; ++s) {
            const float* hr = hs + (size_t)toks[s] * HID;
#pragma unroll
            for (int i = 0; i < 4; ++i) {
                const int f4 = i * 256 + tid;
                *(float4*)&hs4[s][f4 * 4] = *(const float4*)(hr + f4 * 4);
            }
        }
        __syncthreads();

        // ---- expert loop: 16 groups of 4 experts per wave ----
        for (int g = 0; g < 16; ++g) {
            const int e0 = w * 64 + g * 4;
            float a[4][4];               // [expert p][token t]
#pragma unroll
            for (int p = 0; p < 4; ++p)
#pragma unroll
                for (int t = 0; t < 4; ++t) a[p][t] = 0.0f;

            for (int j = 0; j < 16; ++j) {
                const int f4 = j * 64 + lane;
                float4 h[4];
#pragma unroll
                for (int t = 0; t < 4; ++t)
                    h[t] = *(const float4*)&hs4[t][f4 * 4];
#pragma unroll
                for (int p = 0; p < 4; ++p) {
                    const float4 b = *(const float4*)(wt + (size_t)(e0 + p) * HID + f4 * 4);
#pragma unroll
                    for (int t = 0; t < 4; ++t) {
                        a[p][t] = fmaf(h[t].x, b.x, a[p][t]);
                        a[p][t] = fmaf(h[t].y, b.y, a[p][t]);
                        a[p][t] = fmaf(h[t].z, b.z, a[p][t]);
                        a[p][t] = fmaf(h[t].w, b.w, a[p][t]);
                    }
                }
            }
            // butterfly reduce across 64 lanes (all lanes end with totals)
#pragma unroll
            for (int p = 0; p < 4; ++p)
#pragma unroll
                for (int t = 0; t < 4; ++t)
#pragma unroll
                    for (int d = 1; d < 64; d <<= 1)
                        a[p][t] += __shfl_xor(a[p][t], d, 64);

            if (lane == 0) {
#pragma unroll
                for (int t = 0; t < 4; ++t)
#pragma unroll
                    for (int p = 0; p < 4; ++p)
                        lgg[(size_t)pos[t] * NEXP + e0 + p] = a[p][t];
            }
        }
        __syncthreads();                 // lgg writes block-visible; hs4 now dead

        // ---- copy lgg -> LDS with sigmoid (parallel), stride-257 rows ----
        float* lg = &hs4[0][0];
        for (int idx = tid; idx < 4 * NEXP; idx += 256) {
            const int t = idx >> 8, e = idx & 255;
            const float x = lgg[(size_t)pos[t] * NEXP + e];
            lg[t * 257 + e] = 1.0f / (1.0f + expf(-x));
        }
        __syncthreads();

        // ---- route flagged tokens ----
        if (tid < (int)n) {
            const int t = toks[tid];
            int id[TOPK]; float wv[TOPK];
            route_core([&](int e) { return lg[tid * 257 + e]; }, bias, id, wv);
            for (int r = 0; r < TOPK; ++r) {
                out[(size_t)t * TOPK + r] = (float)id[r];
                out[(size_t)T_TOKENS * TOPK + (size_t)t * TOPK + r] = wv[r];
            }
        }
    }
}

// =============== slow cleanup (mid-tier fallback only; R6 code) ===============
__global__ __launch_bounds__(256, 2)
void router_exact_small(const float* __restrict__ hs, const float* __restrict__ wt,
                        const float* __restrict__ bias, float* __restrict__ out,
                        const unsigned* __restrict__ wcnt, const unsigned* __restrict__ wlist,
                        unsigned cap)
{
    __shared__ float lg[8][NEXP + 1];
    __shared__ int   toks[8];
    const unsigned count = min(*wcnt, cap);
    const int tid = threadIdx.x;

    for (unsigned base = blockIdx.x * 8u; base < count; base += gridDim.x * 8u) {
        const unsigned n = min(8u, count - base);
        __syncthreads();
        if (tid < 8) toks[tid] = (int)wlist[base + min((unsigned)tid, n - 1)];
        __syncthreads();

        const float* wr = wt + (size_t)tid * HID;
        const float* hp[8];
#pragma unroll
        for (int j = 0; j < 8; ++j) hp[j] = hs + (size_t)toks[j] * HID;

        float a[8] = {0.f, 0.f, 0.f, 0.f, 0.f, 0.f, 0.f, 0.f};
        for (int k = 0; k < HID; k += 4) {
            const float4 b = *(const float4*)(wr + k);
#pragma unroll
            for (int j = 0; j < 8; ++j) {
                const float4 x = *(const float4*)(hp[j] + k);
                a[j] = fmaf(x.x, b.x, a[j]); a[j] = fmaf(x.y, b.y, a[j]);
                a[j] = fmaf(x.z, b.z, a[j]); a[j] = fmaf(x.w, b.w, a[j]);
            }
        }
#pragma unroll
        for (int j = 0; j < 8; ++j) lg[j][tid] = 1.0f / (1.0f + expf(-a[j]));
        __syncthreads();

        if (tid < (int)n) {
            const int t = toks[tid];
            int id[TOPK]; float wv[TOPK];
            route_core([&](int e) { return lg[tid][e]; }, bias, id, wv);
            for (int r = 0; r < TOPK; ++r) {
                out[(size_t)t * TOPK + r] = (float)id[r];
                out[(size_t)T_TOKENS * TOPK + (size_t)t * TOPK + r] = wv[r];
            }
        }
    }
}

// =============== fallback monolith (R5-validated, unchanged) ===============
__global__ __launch_bounds__(512, 1)
void router_mono(const float* __restrict__ hs, const float* __restrict__ wt,
                 const float* __restrict__ bias, float* __restrict__ out,
                 unsigned* __restrict__ wcnt, unsigned* __restrict__ wlist, unsigned cap)
{
    __shared__ float smem[16384];
    ushort* u16 = (ushort*)smem;
    float*  Lg  = smem;

    const int tid  = threadIdx.x;
    const int lane = tid & 63;
    const int w    = tid >> 6;
    const int t0   = blockIdx.x * 64;
    const int ar   = tid >> 3;
    const int aq   = tid & 7;

    f32x4 acc[4][2];
#pragma unroll
    for (int i = 0; i < 4; ++i)
#pragma unroll
        for (int j = 0; j < 2; ++j) acc[i][j] = (f32x4)0.0f;

    float4 ra, rb[4];
    ra = *(const float4*)(hs + (size_t)(t0 + ar) * HID + aq * 4);
#pragma unroll
    for (int s = 0; s < 4; ++s)
        rb[s] = *(const float4*)(wt + (size_t)(ar + s * 64) * HID + aq * 4);

    for (int ks = 0; ks < HID / BK; ++ks) {
        __syncthreads();
        {
            uint h01, h23, l01, l23;
            split4(ra, h01, h23, l01, l23);
            const int eo = (ar >> 4) * 512 + (aq >> 1) * 128 + (ar & 15) * 8 + (aq & 1) * 4;
            uint2 hv; hv.x = h01; hv.y = h23;
            uint2 lv; lv.x = l01; lv.y = l23;
            *(uint2*)&u16[0 + eo] = hv;
            *(uint2*)&u16[2048 + eo] = lv;
        }
#pragma unroll
        for (int s = 0; s < 4; ++s) {
            const int e = ar + s * 64;
            uint h01, h23, l01, l23;
            split4(rb[s], h01, h23, l01, l23);
            const int eo = (e >> 4) * 512 + (aq >> 1) * 128 + (e & 15) * 8 + (aq & 1) * 4;
            uint2 hv; hv.x = h01; hv.y = h23;
            uint2 lv; lv.x = l01; lv.y = l23;
            *(uint2*)&u16[4096 + eo] = hv;
            *(uint2*)&u16[12288 + eo] = lv;
        }
        __syncthreads();
        if (ks + 1 < HID / BK) {
            const int k0 = (ks + 1) * BK;
            ra = *(const float4*)(hs + (size_t)(t0 + ar) * HID + k0 + aq * 4);
#pragma unroll
            for (int s = 0; s < 4; ++s)
                rb[s] = *(const float4*)(wt + (size_t)(ar + s * 64) * HID + k0 + aq * 4);
        }
        bf16x8 ah[4], al[4];
#pragma unroll
        for (int rt = 0; rt < 4; ++rt) {
            ah[rt] = *(const bf16x8*)&u16[0 + rt * 512 + lane * 8];
            al[rt] = *(const bf16x8*)&u16[2048 + rt * 512 + lane * 8];
        }
#pragma unroll
        for (int c = 0; c < 2; ++c) {
            const int ct = w * 2 + c;
            const bf16x8 bh = *(const bf16x8*)&u16[4096 + ct * 512 + lane * 8];
            const bf16x8 bl = *(const bf16x8*)&u16[12288 + ct * 512 + lane * 8];
#pragma unroll
            for (int rt = 0; rt < 4; ++rt) {
                acc[rt][c] = __builtin_amdgcn_mfma_f32_16x16x32_bf16(ah[rt], bh, acc[rt][c], 0, 0, 0);
                acc[rt][c] = __builtin_amdgcn_mfma_f32_16x16x32_bf16(ah[rt], bl, acc[rt][c], 0, 0, 0);
                acc[rt][c] = __builtin_amdgcn_mfma_f32_16x16x32_bf16(al[rt], bh, acc[rt][c], 0, 0, 0);
            }
        }
    }
    __syncthreads();
#pragma unroll
    for (int rt = 0; rt < 4; ++rt)
#pragma unroll
        for (int c = 0; c < 2; ++c) {
            const int col  = w * 32 + c * 16 + (lane & 15);
            const int rowb = rt * 16 + (lane >> 4) * 4;
#pragma unroll
            for (int j = 0; j < 4; ++j) {
                const int row = rowb + j;
                Lg[col * 64 + ((row + col) & 63)] = 1.0f / (1.0f + expf(-acc[rt][c][j]));
            }
        }
    __syncthreads();

    if (tid < 64) {
        const int t = t0 + tid;
        int id[TOPK]; float wv[TOPK];
        const bool tight = route_core(
            [&](int e) { return Lg[e * 64 + ((tid + e) & 63)]; }, bias, id, wv);
#pragma unroll
        for (int r = 0; r < TOPK; ++r) {
            out[(size_t)t * TOPK + r] = (float)id[r];
            out[(size_t)T_TOKENS * TOPK + (size_t)t * TOPK + r] = wv[r];
        }
        if (tight) {
            bool queued = false;
            if (wcnt) {
                const unsigned pos = atomicAdd(wcnt, 1u);
                if (pos < cap) { wlist[pos] = (unsigned)t; queued = true; }
            }
            if (!queued) exact_token(hs, wt, bias, out, t);
        }
    }
}

extern "C" void kernel_launch(void* const* d_in, const int* in_sizes, int n_in,
                              void* d_out, int out_size, void* d_ws, size_t ws_size,
                              hipStream_t stream) {
    const float* hs   = (const float*)d_in[0];   // [16384, 4096] f32
    const float* wt   = (const float*)d_in[1];   // [256, 4096]   f32
    const float* bias = (const float*)d_in[2];   // [256]         f32
    float* out = (float*)d_out;
    (void)in_sizes; (void)n_in; (void)out_size;

    const size_t PW_BYTES = (size_t)SPLITK * T_TOKENS * NEXP * 4;   // 64 MB
    const size_t NEED = PW_BYTES + 4 + (size_t)T_TOKENS * 4;        // same as R6

    if (ws_size >= NEED) {
        float*    pw    = (float*)d_ws;
        float*    lgg   = (float*)d_ws;          // aliases pw: dead after router_route
        unsigned* wcnt  = (unsigned*)((char*)d_ws + PW_BYTES);
        unsigned* wlist = wcnt + 1;
        hipMemsetAsync(wcnt, 0, sizeof(unsigned), stream);
        router_gemm<<<(T_TOKENS / BM) * SPLITK, 256, 0, stream>>>(hs, wt, pw);
        router_route<<<T_TOKENS / 64, 256, 0, stream>>>(pw, bias, out, wcnt, wlist,
                                                        (unsigned)T_TOKENS);
        router_exact<<<256, 256, 0, stream>>>(hs, wt, bias, out, wcnt, wlist, lgg,
                                              (unsigned)T_TOKENS);
    } else if (ws_size >= 8) {
        unsigned cap = (unsigned)((ws_size - 4) / 4);
        if (cap > T_TOKENS) cap = T_TOKENS;
        unsigned* wcnt  = (unsigned*)d_ws;
        unsigned* wlist = wcnt + 1;
        hipMemsetAsync(d_ws, 0, sizeof(unsigned), stream);
        router_mono<<<T_TOKENS / 64, 512, 0, stream>>>(hs, wt, bias, out, wcnt, wlist, cap);
        router_exact_small<<<256, 256, 0, stream>>>(hs, wt, bias, out, wcnt, wlist, cap);
    } else {
        router_mono<<<T_TOKENS / 64, 512, 0, stream>>>(hs, wt, bias, out,
                                                       nullptr, nullptr, 0u);
    }
}

// Round 8
// 353.058 us; speedup vs baseline: 1.8808x; 1.2747x over previous
//
#include <hip/hip_runtime.h>
#include <math.h>

#define T_TOKENS 16384
#define HID      4096
#define NEXP     256
#define NGROUP   8
#define GSIZE    32
#define TOPKG    4
#define TOPK     8
#define RSCALE   2.5f

#define TAU   2e-5f      // expert-score margin (validated R5-R7)
#define TAUG  3e-5f      // group-score margin  (validated R5-R7)

// ---- split-K GEMM config (unchanged from R6/R7, known-good) ----
#define BM     64
#define BK     32
#define SPLITK 4
#define KSPAN  (HID / SPLITK)    // 1024
#define NKS    (KSPAN / BK)      // 32 K-steps per block
#define CSTR   136
#define TSTR   544
#define A_HI   0
#define A_LO   2176
#define B_HI   4352
#define B_LO   13056
#define STG_TOT 21760            // ushorts = 43520 B

typedef __attribute__((ext_vector_type(8))) short bf16x8;
typedef __attribute__((ext_vector_type(4))) float f32x4;

__device__ __forceinline__ int stoff(int r, int q) {
    return (r >> 4) * TSTR + (q >> 1) * CSTR + (r & 15) * 8 + (q & 1) * 4;
}
__device__ __forceinline__ int froff(int lane) {
    return (lane >> 4) * CSTR + (lane & 15) * 8;
}

__device__ __forceinline__ void split4(const float4 v, uint& h01, uint& h23,
                                       uint& l01, uint& l23) {
    const uint u0 = __float_as_uint(v.x) + 0x8000u;
    const uint u1 = __float_as_uint(v.y) + 0x8000u;
    const uint u2 = __float_as_uint(v.z) + 0x8000u;
    const uint u3 = __float_as_uint(v.w) + 0x8000u;
    h01 = __builtin_amdgcn_perm(u1, u0, 0x07060302u);
    h23 = __builtin_amdgcn_perm(u3, u2, 0x07060302u);
    const float f0 = v.x - __uint_as_float(u0 & 0xFFFF0000u);
    const float f1 = v.y - __uint_as_float(u1 & 0xFFFF0000u);
    const float f2 = v.z - __uint_as_float(u2 & 0xFFFF0000u);
    const float f3 = v.w - __uint_as_float(u3 & 0xFFFF0000u);
    l01 = __builtin_amdgcn_perm(__float_as_uint(f1) + 0x8000u,
                                __float_as_uint(f0) + 0x8000u, 0x07060302u);
    l23 = __builtin_amdgcn_perm(__float_as_uint(f3) + 0x8000u,
                                __float_as_uint(f2) + 0x8000u, 0x07060302u);
}

// ---- shared routing decision (identical in all paths; validated R5-R7) ----
template <class SC>
__device__ __forceinline__ bool route_core(SC sc, const float* __restrict__ bias,
                                           int* id, float* wv)
{
    float gs[NGROUP];
#pragma unroll
    for (int g = 0; g < NGROUP; ++g) {
        float m1 = -1e30f, m2 = -1e30f;
        for (int i = 0; i < GSIZE; ++i) {
            const int e = g * GSIZE + i;
            const float v = sc(e) + bias[e];
            if (v > m1)      { m2 = m1; m1 = v; }
            else if (v > m2) { m2 = v; }
        }
        gs[g] = m1 + m2;
    }

    unsigned gmask = 0;
    float g4 = -1e30f;
#pragma unroll
    for (int r = 0; r < TOPKG; ++r) {
        int bi = 0; float bv = -1e30f;
#pragma unroll
        for (int g = 0; g < NGROUP; ++g) {
            const bool taken = (gmask >> g) & 1;
            if (!taken && gs[g] > bv) { bv = gs[g]; bi = g; }
        }
        gmask |= 1u << bi;
        g4 = bv;
    }
    float g5 = -1e30f;
#pragma unroll
    for (int g = 0; g < NGROUP; ++g)
        if (!((gmask >> g) & 1) && gs[g] > g5) g5 = gs[g];

    float val[TOPK + 1]; int vid[TOPK + 1];
#pragma unroll
    for (int r = 0; r <= TOPK; ++r) { val[r] = -1e30f; vid[r] = 0; }
    for (int e = 0; e < NEXP; ++e) {
        const bool allowed = (gmask >> (e >> 5)) & 1;
        const float v = allowed ? (sc(e) + bias[e]) : 0.0f;
        if (v > val[TOPK]) {
#pragma unroll
            for (int p = TOPK; p >= 1; --p) {
                if (v > val[p - 1])  { val[p] = val[p - 1]; vid[p] = vid[p - 1]; }
                else if (v > val[p]) { val[p] = v;          vid[p] = e; }
            }
            if (v > val[0]) { val[0] = v; vid[0] = e; }
        }
    }

    bool tight = (g4 - g5 < TAUG);
#pragma unroll
    for (int i = 0; i < TOPK; ++i) tight |= (val[i] - val[i + 1] < TAU);

    float sum = 0.0f;
#pragma unroll
    for (int r = 0; r < TOPK; ++r) { id[r] = vid[r]; wv[r] = sc(vid[r]); sum += wv[r]; }
    const float inv = RSCALE / (sum + 1e-20f);
#pragma unroll
    for (int r = 0; r < TOPK; ++r) wv[r] *= inv;
    return tight;
}

// exact fp32 recompute + route for one token (cold fallback only)
__device__ void exact_token(const float* __restrict__ hs, const float* __restrict__ wt,
                            const float* __restrict__ bias, float* __restrict__ out, int t)
{
    float lg[NEXP];
    const float* hrow = hs + (size_t)t * HID;
    for (int e = 0; e < NEXP; ++e) {
        const float* wr = wt + (size_t)e * HID;
        float a = 0.0f;
        for (int k = 0; k < HID; k += 4) {
            const float4 x = *(const float4*)(hrow + k);
            const float4 b = *(const float4*)(wr + k);
            a = fmaf(x.x, b.x, a); a = fmaf(x.y, b.y, a);
            a = fmaf(x.z, b.z, a); a = fmaf(x.w, b.w, a);
        }
        lg[e] = 1.0f / (1.0f + expf(-a));
    }
    int id[TOPK]; float wv[TOPK];
    route_core([&](int e) { return lg[e]; }, bias, id, wv);
    for (int r = 0; r < TOPK; ++r) {
        out[(size_t)t * TOPK + r] = (float)id[r];
        out[(size_t)T_TOKENS * TOPK + (size_t)t * TOPK + r] = wv[r];
    }
}

// =============== split-K GEMM: partial logits -> pw[s][t][e] (unchanged) ===============
__global__ __launch_bounds__(256, 2)
void router_gemm(const float* __restrict__ hs, const float* __restrict__ wt,
                 float* __restrict__ pw)
{
    __shared__ ushort u16[STG_TOT];

    const int tid  = threadIdx.x;
    const int lane = tid & 63;
    const int w    = tid >> 6;
    const int m    = blockIdx.x >> 2;
    const int sk   = blockIdx.x & 3;
    const int t0   = m * BM;
    const int kb0  = sk * KSPAN;
    const int r0   = tid >> 3;
    const int q    = tid & 7;

    f32x4 acc[4][4];
#pragma unroll
    for (int i = 0; i < 4; ++i)
#pragma unroll
        for (int j = 0; j < 4; ++j) acc[i][j] = (f32x4)0.0f;

    float4 ra[2], rb[8];
#pragma unroll
    for (int s = 0; s < 2; ++s)
        ra[s] = *(const float4*)(hs + (size_t)(t0 + r0 + 32 * s) * HID + kb0 + q * 4);
#pragma unroll
    for (int i = 0; i < 8; ++i)
        rb[i] = *(const float4*)(wt + (size_t)(r0 + 32 * i) * HID + kb0 + q * 4);

    for (int ks = 0; ks < NKS; ++ks) {
        __syncthreads();

#pragma unroll
        for (int s = 0; s < 2; ++s) {
            const int r = r0 + 32 * s;
            uint h01, h23, l01, l23;
            split4(ra[s], h01, h23, l01, l23);
            const int eo = stoff(r, q);
            uint2 hv; hv.x = h01; hv.y = h23;
            uint2 lv; lv.x = l01; lv.y = l23;
            *(uint2*)&u16[A_HI + eo] = hv;
            *(uint2*)&u16[A_LO + eo] = lv;
        }
#pragma unroll
        for (int i = 0; i < 8; ++i) {
            const int r = r0 + 32 * i;
            uint h01, h23, l01, l23;
            split4(rb[i], h01, h23, l01, l23);
            const int eo = stoff(r, q);
            uint2 hv; hv.x = h01; hv.y = h23;
            uint2 lv; lv.x = l01; lv.y = l23;
            *(uint2*)&u16[B_HI + eo] = hv;
            *(uint2*)&u16[B_LO + eo] = lv;
        }
        __syncthreads();

        if (ks + 1 < NKS) {
            const int kb = kb0 + (ks + 1) * BK;
#pragma unroll
            for (int s = 0; s < 2; ++s)
                ra[s] = *(const float4*)(hs + (size_t)(t0 + r0 + 32 * s) * HID + kb + q * 4);
#pragma unroll
            for (int i = 0; i < 8; ++i)
                rb[i] = *(const float4*)(wt + (size_t)(r0 + 32 * i) * HID + kb + q * 4);
        }

        const int fo = froff(lane);
        bf16x8 ah[4], al[4];
#pragma unroll
        for (int rt = 0; rt < 4; ++rt) {
            ah[rt] = *(const bf16x8*)&u16[A_HI + rt * TSTR + fo];
            al[rt] = *(const bf16x8*)&u16[A_LO + rt * TSTR + fo];
        }
#pragma unroll
        for (int c = 0; c < 4; ++c) {
            const int ct = w * 4 + c;
            const bf16x8 bh = *(const bf16x8*)&u16[B_HI + ct * TSTR + fo];
            const bf16x8 bl = *(const bf16x8*)&u16[B_LO + ct * TSTR + fo];
#pragma unroll
            for (int rt = 0; rt < 4; ++rt) {
                acc[rt][c] = __builtin_amdgcn_mfma_f32_16x16x32_bf16(ah[rt], bh, acc[rt][c], 0, 0, 0);
                acc[rt][c] = __builtin_amdgcn_mfma_f32_16x16x32_bf16(ah[rt], bl, acc[rt][c], 0, 0, 0);
                acc[rt][c] = __builtin_amdgcn_mfma_f32_16x16x32_bf16(al[rt], bh, acc[rt][c], 0, 0, 0);
            }
        }
    }

#pragma unroll
    for (int rt = 0; rt < 4; ++rt)
#pragma unroll
        for (int c = 0; c < 4; ++c) {
            const int col  = w * 64 + c * 16 + (lane & 15);
            const int rowb = rt * 16 + (lane >> 4) * 4;
#pragma unroll
            for (int j = 0; j < 4; ++j)
                pw[((size_t)(sk * T_TOKENS) + t0 + rowb + j) * NEXP + col] = acc[rt][c][j];
        }
}

// =============== routing: sum partials -> sigmoid -> route (unchanged) ===============
__global__ __launch_bounds__(256, 2)
void router_route(const float* __restrict__ pw, const float* __restrict__ bias,
                  float* __restrict__ out,
                  unsigned* __restrict__ wcnt, unsigned* __restrict__ wlist,
                  unsigned cap)
{
    __shared__ float Lg[NEXP * 64];
    const int tid = threadIdx.x;
    const int t0  = blockIdx.x * 64;

#pragma unroll 8
    for (int t = 0; t < 64; ++t) {
        float v = 0.0f;
#pragma unroll
        for (int s = 0; s < SPLITK; ++s)
            v += pw[((size_t)(s * T_TOKENS) + t0 + t) * NEXP + tid];
        Lg[tid * 64 + ((t + tid) & 63)] = 1.0f / (1.0f + expf(-v));
    }
    __syncthreads();

    if (tid < 64) {
        const int t = t0 + tid;
        int id[TOPK]; float wv[TOPK];
        const bool tight = route_core(
            [&](int e) { return Lg[e * 64 + ((tid + e) & 63)]; }, bias, id, wv);

#pragma unroll
        for (int r = 0; r < TOPK; ++r) {
            out[(size_t)t * TOPK + r] = (float)id[r];
            out[(size_t)T_TOKENS * TOPK + (size_t)t * TOPK + r] = wv[r];
        }
        if (tight) {
            const unsigned pos = atomicAdd(wcnt, 1u);
            if (pos < cap) wlist[pos] = (unsigned)t;
        }
    }
}

// =============== cleanup v3: one token per block, deep-issue, high TLP ===============
// ~850 flagged tokens -> ~850 active blocks (3-4/CU). Wave w owns experts
// w*64..+63 in groups of 4; j-loop unrolled 4x -> 16 weight float4 in flight.
__global__ __launch_bounds__(256, 4)
void router_exact(const float* __restrict__ hs, const float* __restrict__ wt,
                  const float* __restrict__ bias, float* __restrict__ out,
                  const unsigned* __restrict__ wcnt, const unsigned* __restrict__ wlist,
                  unsigned cap)
{
    __shared__ float hrow[HID];          // 16 KB
    __shared__ float lg[NEXP];           // 1 KB
    const unsigned count = min(*wcnt, cap);
    const int tid  = threadIdx.x;
    const int lane = tid & 63;
    const int w    = tid >> 6;

    for (unsigned b = blockIdx.x; b < count; b += gridDim.x) {
        __syncthreads();                 // guard hrow/lg reuse across passes
        const int t = (int)wlist[b];

        // stage hs row (coalesced float4, 4 per thread)
#pragma unroll
        for (int i = 0; i < 4; ++i) {
            const int f4 = i * 256 + tid;
            *(float4*)&hrow[f4 * 4] = *(const float4*)(hs + (size_t)t * HID + f4 * 4);
        }
        __syncthreads();

        for (int g = 0; g < 16; ++g) {
            const int e0 = w * 64 + g * 4;
            float a[4] = {0.0f, 0.0f, 0.0f, 0.0f};
#pragma unroll 4
            for (int j = 0; j < 16; ++j) {
                const int f4 = j * 64 + lane;
                const float4 h = *(const float4*)&hrow[f4 * 4];
#pragma unroll
                for (int p = 0; p < 4; ++p) {
                    const float4 v = *(const float4*)(wt + (size_t)(e0 + p) * HID + f4 * 4);
                    a[p] = fmaf(h.x, v.x, a[p]); a[p] = fmaf(h.y, v.y, a[p]);
                    a[p] = fmaf(h.z, v.z, a[p]); a[p] = fmaf(h.w, v.w, a[p]);
                }
            }
            // butterfly reduce across 64 lanes
#pragma unroll
            for (int p = 0; p < 4; ++p)
#pragma unroll
                for (int d = 1; d < 64; d <<= 1)
                    a[p] += __shfl_xor(a[p], d, 64);
            if (lane == 0) {
#pragma unroll
                for (int p = 0; p < 4; ++p)
                    lg[e0 + p] = 1.0f / (1.0f + expf(-a[p]));
            }
        }
        __syncthreads();

        if (tid == 0) {
            int id[TOPK]; float wv[TOPK];
            route_core([&](int e) { return lg[e]; }, bias, id, wv);
            for (int r = 0; r < TOPK; ++r) {
                out[(size_t)t * TOPK + r] = (float)id[r];
                out[(size_t)T_TOKENS * TOPK + (size_t)t * TOPK + r] = wv[r];
            }
        }
    }
}

// =============== fallback monolith (R5-validated, unchanged) ===============
__global__ __launch_bounds__(512, 1)
void router_mono(const float* __restrict__ hs, const float* __restrict__ wt,
                 const float* __restrict__ bias, float* __restrict__ out,
                 unsigned* __restrict__ wcnt, unsigned* __restrict__ wlist, unsigned cap)
{
    __shared__ float smem[16384];
    ushort* u16 = (ushort*)smem;
    float*  Lg  = smem;

    const int tid  = threadIdx.x;
    const int lane = tid & 63;
    const int w    = tid >> 6;
    const int t0   = blockIdx.x * 64;
    const int ar   = tid >> 3;
    const int aq   = tid & 7;

    f32x4 acc[4][2];
#pragma unroll
    for (int i = 0; i < 4; ++i)
#pragma unroll
        for (int j = 0; j < 2; ++j) acc[i][j] = (f32x4)0.0f;

    float4 ra, rb[4];
    ra = *(const float4*)(hs + (size_t)(t0 + ar) * HID + aq * 4);
#pragma unroll
    for (int s = 0; s < 4; ++s)
        rb[s] = *(const float4*)(wt + (size_t)(ar + s * 64) * HID + aq * 4);

    for (int ks = 0; ks < HID / BK; ++ks) {
        __syncthreads();
        {
            uint h01, h23, l01, l23;
            split4(ra, h01, h23, l01, l23);
            const int eo = (ar >> 4) * 512 + (aq >> 1) * 128 + (ar & 15) * 8 + (aq & 1) * 4;
            uint2 hv; hv.x = h01; hv.y = h23;
            uint2 lv; lv.x = l01; lv.y = l23;
            *(uint2*)&u16[0 + eo] = hv;
            *(uint2*)&u16[2048 + eo] = lv;
        }
#pragma unroll
        for (int s = 0; s < 4; ++s) {
            const int e = ar + s * 64;
            uint h01, h23, l01, l23;
            split4(rb[s], h01, h23, l01, l23);
            const int eo = (e >> 4) * 512 + (aq >> 1) * 128 + (e & 15) * 8 + (aq & 1) * 4;
            uint2 hv; hv.x = h01; hv.y = h23;
            uint2 lv; lv.x = l01; lv.y = l23;
            *(uint2*)&u16[4096 + eo] = hv;
            *(uint2*)&u16[12288 + eo] = lv;
        }
        __syncthreads();
        if (ks + 1 < HID / BK) {
            const int k0 = (ks + 1) * BK;
            ra = *(const float4*)(hs + (size_t)(t0 + ar) * HID + k0 + aq * 4);
#pragma unroll
            for (int s = 0; s < 4; ++s)
                rb[s] = *(const float4*)(wt + (size_t)(ar + s * 64) * HID + k0 + aq * 4);
        }
        bf16x8 ah[4], al[4];
#pragma unroll
        for (int rt = 0; rt < 4; ++rt) {
            ah[rt] = *(const bf16x8*)&u16[0 + rt * 512 + lane * 8];
            al[rt] = *(const bf16x8*)&u16[2048 + rt * 512 + lane * 8];
        }
#pragma unroll
        for (int c = 0; c < 2; ++c) {
            const int ct = w * 2 + c;
            const bf16x8 bh = *(const bf16x8*)&u16[4096 + ct * 512 + lane * 8];
            const bf16x8 bl = *(const bf16x8*)&u16[12288 + ct * 512 + lane * 8];
#pragma unroll
            for (int rt = 0; rt < 4; ++rt) {
                acc[rt][c] = __builtin_amdgcn_mfma_f32_16x16x32_bf16(ah[rt], bh, acc[rt][c], 0, 0, 0);
                acc[rt][c] = __builtin_amdgcn_mfma_f32_16x16x32_bf16(ah[rt], bl, acc[rt][c], 0, 0, 0);
                acc[rt][c] = __builtin_amdgcn_mfma_f32_16x16x32_bf16(al[rt], bh, acc[rt][c], 0, 0, 0);
            }
        }
    }
    __syncthreads();
#pragma unroll
    for (int rt = 0; rt < 4; ++rt)
#pragma unroll
        for (int c = 0; c < 2; ++c) {
            const int col  = w * 32 + c * 16 + (lane & 15);
            const int rowb = rt * 16 + (lane >> 4) * 4;
#pragma unroll
            for (int j = 0; j < 4; ++j) {
                const int row = rowb + j;
                Lg[col * 64 + ((row + col) & 63)] = 1.0f / (1.0f + expf(-acc[rt][c][j]));
            }
        }
    __syncthreads();

    if (tid < 64) {
        const int t = t0 + tid;
        int id[TOPK]; float wv[TOPK];
        const bool tight = route_core(
            [&](int e) { return Lg[e * 64 + ((tid + e) & 63)]; }, bias, id, wv);
#pragma unroll
        for (int r = 0; r < TOPK; ++r) {
            out[(size_t)t * TOPK + r] = (float)id[r];
            out[(size_t)T_TOKENS * TOPK + (size_t)t * TOPK + r] = wv[r];
        }
        if (tight) {
            bool queued = false;
            if (wcnt) {
                const unsigned pos = atomicAdd(wcnt, 1u);
                if (pos < cap) { wlist[pos] = (unsigned)t; queued = true; }
            }
            if (!queued) exact_token(hs, wt, bias, out, t);
        }
    }
}

extern "C" void kernel_launch(void* const* d_in, const int* in_sizes, int n_in,
                              void* d_out, int out_size, void* d_ws, size_t ws_size,
                              hipStream_t stream) {
    const float* hs   = (const float*)d_in[0];   // [16384, 4096] f32
    const float* wt   = (const float*)d_in[1];   // [256, 4096]   f32
    const float* bias = (const float*)d_in[2];   // [256]         f32
    float* out = (float*)d_out;
    (void)in_sizes; (void)n_in; (void)out_size;

    const size_t PW_BYTES = (size_t)SPLITK * T_TOKENS * NEXP * 4;   // 64 MB
    const size_t NEED = PW_BYTES + 4 + (size_t)T_TOKENS * 4;

    if (ws_size >= NEED) {
        float*    pw    = (float*)d_ws;
        unsigned* wcnt  = (unsigned*)((char*)d_ws + PW_BYTES);
        unsigned* wlist = wcnt + 1;
        hipMemsetAsync(wcnt, 0, sizeof(unsigned), stream);
        router_gemm<<<(T_TOKENS / BM) * SPLITK, 256, 0, stream>>>(hs, wt, pw);
        router_route<<<T_TOKENS / 64, 256, 0, stream>>>(pw, bias, out, wcnt, wlist,
                                                        (unsigned)T_TOKENS);
        router_exact<<<2048, 256, 0, stream>>>(hs, wt, bias, out, wcnt, wlist,
                                               (unsigned)T_TOKENS);
    } else if (ws_size >= 8) {
        unsigned cap = (unsigned)((ws_size - 4) / 4);
        if (cap > T_TOKENS) cap = T_TOKENS;
        unsigned* wcnt  = (unsigned*)d_ws;
        unsigned* wlist = wcnt + 1;
        hipMemsetAsync(d_ws, 0, sizeof(unsigned), stream);
        router_mono<<<T_TOKENS / 64, 512, 0, stream>>>(hs, wt, bias, out, wcnt, wlist, cap);
        router_exact<<<2048, 256, 0, stream>>>(hs, wt, bias, out, wcnt, wlist, cap);
    } else {
        router_mono<<<T_TOKENS / 64, 512, 0, stream>>>(hs, wt, bias, out,
                                                       nullptr, nullptr, 0u);
    }
}